// Round 3
// baseline (678.513 us; speedup 1.0000x reference)
//
#include <hip/hip_runtime.h>

// NURBS cubic surface eval: S*F=32 surfaces, 32x32 CPs, degree 3, uniform
// clamped knots. Outputs: pt [SF,P,3] and normalized normal [SF,P,3].
//
// Round-3 structure (post-mortem R2: ~76us kernel, no pipe saturated ->
// latency-bound serial dependency chain per point):
//  - 2 points/thread, unrolled: two independent chains per wave for ILP;
//    ev load becomes one float4; stores become 3x dwordx2 per array (dense).
//  - Knot-unit basis: all 29-scalings cancel; derivative scale 3*29 dropped
//    entirely (only normalized normals are output -> uniform du/dv scale
//    cancels in cross+normalize).
//  - LDS sliding windows (R2): win[row][c] = CPs [row][c..c+3] xyz-interleaved
//    as 3 aligned float4 -> 12 ds_read_b128/point, one addr reg + immediates.
//  - 512-thr blocks, launch_bounds(512,6): 3 blocks/CU (144KB LDS), 24 waves.

#define NCP 32

// Cubic B-spline basis (values B0, UNSCALED first-deriv shape B1) on the
// uniform clamped knot grid, in knot-interval units. U = u*29 in [0,29).
// B1 is the true derivative divided by 3*29 (uniform factor, cancels in
// the normal's normalize).
__device__ __forceinline__ void basis3u(float U, float B0[4], float B1[4], int& A)
{
    float Af = floorf(U);
    A = (int)Af;
    float t  = U - Af;                 // local coord in [0,1)
    float c1 = fminf(Af, 1.0f);        // left clamp counts
    float c2 = fminf(Af, 2.0f);
    float gg = 29.0f - Af;             // intervals to the right end
    float e1 = fminf(gg, 2.0f);
    float e2 = fminf(gg, 3.0f);
    float L1 = t, L2 = t + c1, L3 = t + c2;
    float R1 = 1.0f - t, R2 = e1 - t, R3 = e2 - t;
    // denominator reciprocals (integer interval counts)
    float q20 = (Af < 1.0f) ? 1.0f : 0.5f;                                   // 1/(1+c1)
    float q21 = (gg < 2.0f) ? 1.0f : 0.5f;                                   // 1/e1
    float q30 = (Af < 1.0f) ? 1.0f : ((Af < 2.0f) ? 0.5f : (1.0f / 3.0f));   // 1/(1+c2)
    float q31 = ((Af < 1.0f) || (gg < 2.0f)) ? 0.5f : (1.0f / 3.0f);         // 1/(e1+c1)
    float q32 = (gg < 2.0f) ? 1.0f : ((gg < 3.0f) ? 0.5f : (1.0f / 3.0f));   // 1/e2
    // A2.3 recursion, dimensionless
    float ta  = R1 * q20;
    float n02 = R1 * ta;
    float sv  = L2 * ta;
    float tb  = L1 * q21;
    float n12 = fmaf(R2, tb, sv);
    float n22 = L1 * tb;
    float t0 = n02 * q30;
    B0[0] = R1 * t0;
    sv = L3 * t0;
    float t1 = n12 * q31;
    B0[1] = fmaf(R2, t1, sv);
    sv = L2 * t1;
    float t2 = n22 * q32;
    B0[2] = fmaf(R3, t2, sv);
    B0[3] = L1 * t2;
    // unscaled derivative shape
    B1[0] = -t0;
    B1[1] = t0 - t1;
    B1[2] = t1 - t2;
    B1[3] = t2;
}

__global__ __launch_bounds__(512, 6) void nurbs_eval_kernel(
    const float4* __restrict__ ev4,  // [SF*P/2] packed (u0,v0,u1,v1)
    const float*  __restrict__ cp,   // [SF*32*32*3]
    float* __restrict__ out_pt,      // [SF*P*3]
    float* __restrict__ out_nrm,     // [SF*P*3]
    int P)
{
    // win[(row*32+c)*3 + q]: q=0:[x0 y0 z0 x1] q=1:[y1 z1 x2 y2] q=2:[z2 x3 y3 z3]
    __shared__ float4 win[NCP * NCP * 3];   // 48 KB

    const int sf = blockIdx.y;
    const float* g = cp + (size_t)sf * (NCP * NCP * 3);
    for (int idx = threadIdx.x; idx < NCP * 29; idx += 512) {
        int row = idx / 29;              // staging only (magic-mul)
        int c   = idx - row * 29;
        const float* r = g + (row * NCP + c) * 3;
        int w = (row * NCP + c) * 3;
        win[w + 0] = make_float4(r[0], r[1], r[2],  r[3]);
        win[w + 1] = make_float4(r[4], r[5], r[6],  r[7]);
        win[w + 2] = make_float4(r[8], r[9], r[10], r[11]);
    }
    __syncthreads();

    const int p2 = (blockIdx.x * 512 + threadIdx.x) * 2;
    if (p2 >= P) return;                 // P even -> both points valid
    const int t2 = sf * P + p2;

    const float4 uv = ev4[t2 >> 1];      // (u0,v0,u1,v1), 16B aligned

    float pr[2][3], nr[2][3];
#pragma unroll
    for (int k = 0; k < 2; ++k) {
        const float u = k ? uv.z : uv.x;
        const float v = k ? uv.w : uv.y;
        int au, av;
        float B0u[4], B1u[4], B0v[4], B1v[4];
        basis3u(u * 29.0f, B0u, B1u, au);
        basis3u(v * 29.0f, B0v, B1v, av);
        const float bv0 = B0v[0], bv1 = B0v[1], bv2 = B0v[2], bv3 = B0v[3];
        const float dv0 = B1v[0], dv1 = B1v[1], dv2 = B1v[2], dv3 = B1v[3];

        float px = 0.f, py = 0.f, pz = 0.f;
        float ux = 0.f, uy = 0.f, uz = 0.f;
        float vx = 0.f, vy = 0.f, vz = 0.f;
        const int base = (au * NCP + av) * 3;
#pragma unroll
        for (int i = 0; i < 4; ++i) {
            const float4 q0 = win[base + i * (NCP * 3) + 0];
            const float4 q1 = win[base + i * (NCP * 3) + 1];
            const float4 q2 = win[base + i * (NCP * 3) + 2];
            const float cx0 = q0.x, cy0 = q0.y, cz0 = q0.z;
            const float cx1 = q0.w, cy1 = q1.x, cz1 = q1.y;
            const float cx2 = q1.z, cy2 = q1.w, cz2 = q2.x;
            const float cx3 = q2.y, cy3 = q2.z, cz3 = q2.w;
            float rpx = fmaf(bv3, cx3, fmaf(bv2, cx2, fmaf(bv1, cx1, bv0 * cx0)));
            float rpy = fmaf(bv3, cy3, fmaf(bv2, cy2, fmaf(bv1, cy1, bv0 * cy0)));
            float rpz = fmaf(bv3, cz3, fmaf(bv2, cz2, fmaf(bv1, cz1, bv0 * cz0)));
            float rvx = fmaf(dv3, cx3, fmaf(dv2, cx2, fmaf(dv1, cx1, dv0 * cx0)));
            float rvy = fmaf(dv3, cy3, fmaf(dv2, cy2, fmaf(dv1, cy1, dv0 * cy0)));
            float rvz = fmaf(dv3, cz3, fmaf(dv2, cz2, fmaf(dv1, cz1, dv0 * cz0)));
            const float bu = B0u[i], du = B1u[i];
            px = fmaf(bu, rpx, px); py = fmaf(bu, rpy, py); pz = fmaf(bu, rpz, pz);
            ux = fmaf(du, rpx, ux); uy = fmaf(du, rpy, uy); uz = fmaf(du, rpz, uz);
            vx = fmaf(bu, rvx, vx); vy = fmaf(bu, rvy, vy); vz = fmaf(bu, rvz, vz);
        }

        // normal = normalize(cross(du,dv)); uniform (3*29)^2 scale cancels
        float nx = uy * vz - uz * vy;
        float ny = uz * vx - ux * vz;
        float nz = ux * vy - uy * vx;
        float d   = fmaf(nx, nx, fmaf(ny, ny, nz * nz));
        float len = __builtin_amdgcn_sqrtf(d);
        float inv = __builtin_amdgcn_rcpf(len + 1e-12f);
        pr[k][0] = px; pr[k][1] = py; pr[k][2] = pz;
        nr[k][0] = nx * inv; nr[k][1] = ny * inv; nr[k][2] = nz * inv;
    }

    // 6 consecutive floats per array per thread -> 3x dwordx2 each, dense
    float2* op = (float2*)(out_pt + (size_t)t2 * 3);
    op[0] = make_float2(pr[0][0], pr[0][1]);
    op[1] = make_float2(pr[0][2], pr[1][0]);
    op[2] = make_float2(pr[1][1], pr[1][2]);
    float2* on = (float2*)(out_nrm + (size_t)t2 * 3);
    on[0] = make_float2(nr[0][0], nr[0][1]);
    on[1] = make_float2(nr[0][2], nr[1][0]);
    on[2] = make_float2(nr[1][1], nr[1][2]);
}

extern "C" void kernel_launch(void* const* d_in, const int* in_sizes, int n_in,
                              void* d_out, int out_size, void* d_ws, size_t ws_size,
                              hipStream_t stream) {
    (void)n_in; (void)d_ws; (void)ws_size; (void)out_size;
    const int SF = in_sizes[1] / (NCP * NCP * 3);   // S*F = 32
    const int P  = in_sizes[0] / (SF * 2);          // 200000 (even)
    const int N  = SF * P;                          // 6.4M points

    const float4* ev4 = (const float4*)d_in[0];
    const float*  cp  = (const float*)d_in[1];
    float* out_pt  = (float*)d_out;
    float* out_nrm = (float*)d_out + (size_t)N * 3;

    dim3 block(512);
    dim3 grid((P + 1023) / 1024, SF);               // 2 points/thread
    nurbs_eval_kernel<<<grid, block, 0, stream>>>(ev4, cp, out_pt, out_nrm, P);
}

// Round 4
// 218.334 us; speedup vs baseline: 3.1077x; 3.1077x over previous
//
#include <hip/hip_runtime.h>

// NURBS cubic surface eval: S*F=32 surfaces, 32x32 CPs, degree 3, uniform
// clamped knots. Outputs: pt [SF,P,3] and normalized normals [SF,P,3].
//
// Round-4 structure (post-mortem R3: runtime-indexed private arrays pr[k]/nr[k]
// went to scratch -> 2.5 GB of HBM spill traffic, 7x regression):
//  - R2-proven skeleton: LDS float4 sliding windows, scalar dword stores,
//    private arrays ONLY with constant indices (R2 compiled to VGPR 28, 0 spill).
//  - 2 points/thread as two sequential inlined evals; each point's results are
//    named scalars stored immediately (no state buffered across points).
//  - Knot-unit basis: 29-scalings cancel; uniform deriv scale 3*29 dropped
//    (cancels in cross+normalize).
//  - win shrunk to 32 rows x 29 cols (43.5 KB): 3 blocks/CU of 512 thr fit.
//  - NO min-waves launch bound (R3's (512,6) VGPR clamp was a spill risk).

#define NCP 32
#define WCOLS 29   // window start columns: av in [0,28]

// Cubic B-spline basis values B0* and UNSCALED first-deriv shape D* on the
// uniform clamped grid, knot-interval units. U = u*29 in [0,29).
// D is true_deriv / (3*29); the uniform factor cancels in normalize.
__device__ __forceinline__ void basis3u(float U, int& A,
    float& B00, float& B01, float& B02, float& B03,
    float& D0,  float& D1,  float& D2,  float& D3)
{
    float Af = floorf(U);
    A = (int)Af;
    float t  = U - Af;                 // local coord in [0,1)
    float c1 = fminf(Af, 1.0f);
    float c2 = fminf(Af, 2.0f);
    float gg = 29.0f - Af;
    float e1 = fminf(gg, 2.0f);
    float e2 = fminf(gg, 3.0f);
    float L1 = t, L2 = t + c1, L3 = t + c2;
    float R1 = 1.0f - t, R2 = e1 - t, R3 = e2 - t;
    float q20 = (Af < 1.0f) ? 1.0f : 0.5f;
    float q21 = (gg < 2.0f) ? 1.0f : 0.5f;
    float q30 = (Af < 1.0f) ? 1.0f : ((Af < 2.0f) ? 0.5f : (1.0f / 3.0f));
    float q31 = ((Af < 1.0f) || (gg < 2.0f)) ? 0.5f : (1.0f / 3.0f);
    float q32 = (gg < 2.0f) ? 1.0f : ((gg < 3.0f) ? 0.5f : (1.0f / 3.0f));
    float ta  = R1 * q20;
    float n02 = R1 * ta;
    float sv  = L2 * ta;
    float tb  = L1 * q21;
    float n12 = fmaf(R2, tb, sv);
    float n22 = L1 * tb;
    float t0 = n02 * q30;
    B00 = R1 * t0;
    sv = L3 * t0;
    float t1 = n12 * q31;
    B01 = fmaf(R2, t1, sv);
    sv = L2 * t1;
    float t2 = n22 * q32;
    B02 = fmaf(R3, t2, sv);
    B03 = L1 * t2;
    D0 = -t0;
    D1 = t0 - t1;
    D2 = t1 - t2;
    D3 = t2;
}

// Evaluate one point from LDS windows. All private arrays are indexed only by
// fully-unrolled (constant) loop indices -> SROA-promoted, no scratch.
__device__ __forceinline__ void eval_point(
    const float4* __restrict__ win, float u, float v,
    float& px, float& py, float& pz,
    float& nx, float& ny, float& nz)
{
    int au, av;
    float B0u[4], B1u[4], B0v[4], B1v[4];
    basis3u(u * 29.0f, au, B0u[0], B0u[1], B0u[2], B0u[3],
                           B1u[0], B1u[1], B1u[2], B1u[3]);
    basis3u(v * 29.0f, av, B0v[0], B0v[1], B0v[2], B0v[3],
                           B1v[0], B1v[1], B1v[2], B1v[3]);
    const float bv0 = B0v[0], bv1 = B0v[1], bv2 = B0v[2], bv3 = B0v[3];
    const float dv0 = B1v[0], dv1 = B1v[1], dv2 = B1v[2], dv3 = B1v[3];

    float sx = 0.f, sy = 0.f, sz = 0.f;   // pt
    float ux = 0.f, uy = 0.f, uz = 0.f;   // d/du (unscaled)
    float vx = 0.f, vy = 0.f, vz = 0.f;   // d/dv (unscaled)
    const int base = (au * WCOLS + av) * 3;
#pragma unroll
    for (int i = 0; i < 4; ++i) {
        const float4 q0 = win[base + i * (WCOLS * 3) + 0];
        const float4 q1 = win[base + i * (WCOLS * 3) + 1];
        const float4 q2 = win[base + i * (WCOLS * 3) + 2];
        const float cx0 = q0.x, cy0 = q0.y, cz0 = q0.z;
        const float cx1 = q0.w, cy1 = q1.x, cz1 = q1.y;
        const float cx2 = q1.z, cy2 = q1.w, cz2 = q2.x;
        const float cx3 = q2.y, cy3 = q2.z, cz3 = q2.w;
        float rpx = fmaf(bv3, cx3, fmaf(bv2, cx2, fmaf(bv1, cx1, bv0 * cx0)));
        float rpy = fmaf(bv3, cy3, fmaf(bv2, cy2, fmaf(bv1, cy1, bv0 * cy0)));
        float rpz = fmaf(bv3, cz3, fmaf(bv2, cz2, fmaf(bv1, cz1, bv0 * cz0)));
        float rvx = fmaf(dv3, cx3, fmaf(dv2, cx2, fmaf(dv1, cx1, dv0 * cx0)));
        float rvy = fmaf(dv3, cy3, fmaf(dv2, cy2, fmaf(dv1, cy1, dv0 * cy0)));
        float rvz = fmaf(dv3, cz3, fmaf(dv2, cz2, fmaf(dv1, cz1, dv0 * cz0)));
        const float bu = B0u[i], du = B1u[i];
        sx = fmaf(bu, rpx, sx); sy = fmaf(bu, rpy, sy); sz = fmaf(bu, rpz, sz);
        ux = fmaf(du, rpx, ux); uy = fmaf(du, rpy, uy); uz = fmaf(du, rpz, uz);
        vx = fmaf(bu, rvx, vx); vy = fmaf(bu, rvy, vy); vz = fmaf(bu, rvz, vz);
    }

    float cxn = uy * vz - uz * vy;
    float cyn = uz * vx - ux * vz;
    float czn = ux * vy - uy * vx;
    float d   = fmaf(cxn, cxn, fmaf(cyn, cyn, czn * czn));
    float len = __builtin_amdgcn_sqrtf(d);
    float inv = __builtin_amdgcn_rcpf(len + 1e-12f);
    px = sx; py = sy; pz = sz;
    nx = cxn * inv; ny = cyn * inv; nz = czn * inv;
}

__global__ __launch_bounds__(512) void nurbs_eval_kernel(
    const float4* __restrict__ ev4,  // [SF*P/2] packed (u0,v0,u1,v1)
    const float*  __restrict__ cp,   // [SF*32*32*3]
    float* __restrict__ out_pt,      // [SF*P*3]
    float* __restrict__ out_nrm,     // [SF*P*3]
    int P)
{
    // win[(row*29+c)*3+q]: CPs [row][c..c+3] xyz-interleaved in 3 float4s
    __shared__ float4 win[NCP * WCOLS * 3];   // 43.5 KB

    const int sf = blockIdx.y;
    const float* g = cp + (size_t)sf * (NCP * NCP * 3);
    for (int idx = threadIdx.x; idx < NCP * WCOLS; idx += 512) {
        int row = idx / WCOLS;            // staging only (magic-mul)
        int c   = idx - row * WCOLS;
        const float* r = g + (row * NCP + c) * 3;
        int w = idx * 3;
        win[w + 0] = make_float4(r[0], r[1], r[2],  r[3]);
        win[w + 1] = make_float4(r[4], r[5], r[6],  r[7]);
        win[w + 2] = make_float4(r[8], r[9], r[10], r[11]);
    }
    __syncthreads();

    const int p2 = (blockIdx.x * 512 + threadIdx.x) * 2;
    if (p2 >= P) return;                  // P even -> both points valid
    const int t2 = sf * P + p2;

    const float4 uv = ev4[t2 >> 1];       // (u0,v0,u1,v1)

    // ---- point A: compute and store immediately (no buffering) ----
    {
        float px, py, pz, nx, ny, nz;
        eval_point(win, uv.x, uv.y, px, py, pz, nx, ny, nz);
        const size_t o = (size_t)t2 * 3;
        out_pt[o + 0] = px;  out_pt[o + 1] = py;  out_pt[o + 2] = pz;
        out_nrm[o + 0] = nx; out_nrm[o + 1] = ny; out_nrm[o + 2] = nz;
    }
    // ---- point B ----
    {
        float px, py, pz, nx, ny, nz;
        eval_point(win, uv.z, uv.w, px, py, pz, nx, ny, nz);
        const size_t o = (size_t)(t2 + 1) * 3;
        out_pt[o + 0] = px;  out_pt[o + 1] = py;  out_pt[o + 2] = pz;
        out_nrm[o + 0] = nx; out_nrm[o + 1] = ny; out_nrm[o + 2] = nz;
    }
}

extern "C" void kernel_launch(void* const* d_in, const int* in_sizes, int n_in,
                              void* d_out, int out_size, void* d_ws, size_t ws_size,
                              hipStream_t stream) {
    (void)n_in; (void)d_ws; (void)ws_size; (void)out_size;
    const int SF = in_sizes[1] / (NCP * NCP * 3);   // S*F = 32
    const int P  = in_sizes[0] / (SF * 2);          // 200000 (even)
    const int N  = SF * P;                          // 6.4M points

    const float4* ev4 = (const float4*)d_in[0];
    const float*  cp  = (const float*)d_in[1];
    float* out_pt  = (float*)d_out;
    float* out_nrm = (float*)d_out + (size_t)N * 3;

    dim3 block(512);
    dim3 grid((P + 1023) / 1024, SF);               // 1024 points per block
    nurbs_eval_kernel<<<grid, block, 0, stream>>>(ev4, cp, out_pt, out_nrm, P);
}